// Round 10
// baseline (1348.102 us; speedup 1.0000x reference)
//
#include <hip/hip_runtime.h>
#include <math.h>

#define B_ROWS 4096
#define NSTR 4
#define C_DIM 4096
#define NC 16384      // NSTR*C_DIM
#define NC4 4096      // NC/4 (float4 per batch row)
#define C4 1024       // C_DIM/4 (float4 per stream)

// async global->LDS DMA, 16B per lane. LDS dest must be wave-uniform base;
// lane l writes base + l*16. Global src is per-lane.
#define ASYNC_COPY16(g, l)                                                     \
    __builtin_amdgcn_global_load_lds(                                         \
        (const __attribute__((address_space(1))) void*)(g),                   \
        (__attribute__((address_space(3))) void*)(l), 16, 0, 0)

// ---------------------------------------------------------------------------
// Kernel 0: repack phi into one contiguous [24][16384] buffer.
// Row order: [pre0..3, post0..3, res0..15]
// ---------------------------------------------------------------------------
__global__ void repack_kernel(
    const float4* __restrict__ pre4,
    const float4* __restrict__ post4,
    const float4* __restrict__ res4,
    float4* __restrict__ phiws4)
{
    const int idx = blockIdx.x * blockDim.x + threadIdx.x;   // 0 .. 24*4096-1
    if (idx >= 24 * NC4) return;
    const int row = idx / NC4;
    const int k4  = idx % NC4;
    float4 v;
    if (row < 4)        v = pre4[row * NC4 + k4];
    else if (row < 8)   v = post4[(row - 4) * NC4 + k4];
    else                v = res4[(row - 8) * NC4 + k4];
    phiws4[idx] = v;
}

// ---------------------------------------------------------------------------
// Kernel 1: projections (UNCHANGED from R9 — real pipeline baseline).
// ---------------------------------------------------------------------------
__global__ __launch_bounds__(512, 4) void proj_kernel(
    const float* __restrict__ x,
    const float* __restrict__ phiws,
    float* __restrict__ dots_part)   // [2][B_ROWS][25]
{
    const float4* __restrict__ x4   = reinterpret_cast<const float4*>(x);
    const float4* __restrict__ phi4 = reinterpret_cast<const float4*>(phiws);

    const int bid  = blockIdx.x;
    const int kb   = bid & 1;            // K-half
    const int b0   = (bid >> 1) * 8;     // first batch row
    const int wave = threadIdx.x >> 6;   // 0..7
    const int lane = threadIdx.x & 63;
    const int wv   = __builtin_amdgcn_readfirstlane(wave);  // SGPR wave id

    __shared__ float4 xs[2][8][256];     // [buf][row][float4] = 64 KB
    __shared__ float  red[8][8][3];      // [wave][row][j]
    __shared__ float  redss[8];          // ssq per row (owned by wave==row)

    const int kbase = kb * 2048;

    const float4* __restrict__ srcw    = x4 + (size_t)(b0 + wave) * NC4 + kbase + lane;
    const float4* __restrict__ phibase = phi4 + (size_t)(wave * 3) * NC4 + kbase + lane;

    float acc[8][3];
#pragma unroll
    for (int r = 0; r < 8; ++r)
#pragma unroll
        for (int j = 0; j < 3; ++j) acc[r][j] = 0.f;
    float ssq = 0.f;

#pragma unroll
    for (int i = 0; i < 4; ++i)
        ASYNC_COPY16(srcw + i * 64, &xs[0][wave][i * 64]);
    __syncthreads();

    int cur = 0;
#pragma unroll 1
    for (int c = 0; c < 8; ++c) {
        if (c < 7) {
#pragma unroll
            for (int i = 0; i < 4; ++i)
                ASYNC_COPY16(srcw + (c + 1) * 256 + i * 64,
                             &xs[cur ^ 1][wave][i * 64]);
        }

        const float4* __restrict__ pb = phibase + c * 256;
#pragma unroll 1
        for (int u = 0; u < 4; ++u) {
            const int ki = u * 64 + lane;

            const float4 p0 = pb[(size_t)0 * NC4 + u * 64];
            const float4 p1 = pb[(size_t)1 * NC4 + u * 64];
            const float4 p2 = pb[(size_t)2 * NC4 + u * 64];

            const float4 xw = xs[cur][wv][ki];
            ssq += xw.x*xw.x + xw.y*xw.y + xw.z*xw.z + xw.w*xw.w;

#pragma unroll
            for (int r = 0; r < 8; ++r) {
                const float4 xv = xs[cur][r][ki];
                acc[r][0] += xv.x*p0.x + xv.y*p0.y + xv.z*p0.z + xv.w*p0.w;
                acc[r][1] += xv.x*p1.x + xv.y*p1.y + xv.z*p1.z + xv.w*p1.w;
                acc[r][2] += xv.x*p2.x + xv.y*p2.y + xv.z*p2.z + xv.w*p2.w;
            }
        }

        __syncthreads();
        cur ^= 1;
    }

#pragma unroll
    for (int r = 0; r < 8; ++r)
#pragma unroll
        for (int j = 0; j < 3; ++j) {
            float v = acc[r][j];
#pragma unroll
            for (int off = 32; off > 0; off >>= 1)
                v += __shfl_xor(v, off, 64);
            acc[r][j] = v;
        }
#pragma unroll
    for (int off = 32; off > 0; off >>= 1)
        ssq += __shfl_xor(ssq, off, 64);

    if (lane == 0) {
#pragma unroll
        for (int r = 0; r < 8; ++r)
#pragma unroll
            for (int j = 0; j < 3; ++j)
                red[wave][r][j] = acc[r][j];
        redss[wave] = ssq;
    }
    __syncthreads();

    const int t = threadIdx.x;
    if (t < 200) {
        const int r = t / 25, o = t % 25;
        float s;
        if (o < 24) s = red[o / 3][r][o % 3];
        else        s = redss[r];
        dots_part[((size_t)kb * B_ROWS + (b0 + r)) * 25 + o] = s;
    }
}

// ---------------------------------------------------------------------------
// DIAGNOSTIC: template ablation of proj_kernel. Writes only to sink (scratch).
//   V=0 full   V=1 no-phi-loads   V=2 no-LDS-reads   V=3 no-DMA   V=4 no-barriers
// 3 internal repeats so each variant exceeds the ~160us harness fills and
// surfaces in the rocprof top-5 with its own counters.
// Anti-DCE (rule #17): all kept loads feed the reduced sink store; skipped
// inputs become r-dependent constants (no reassociation w/o fast-math).
// ---------------------------------------------------------------------------
template<int V>
__global__ __launch_bounds__(512, 4) void proj_abl(
    const float* __restrict__ x,
    const float* __restrict__ phiws,
    float* __restrict__ sink)
{
    constexpr bool USE_PHI  = (V != 1);
    constexpr bool USE_LDSR = (V != 2);
    constexpr bool USE_DMA  = (V != 3);
    constexpr bool USE_BAR  = (V != 4);

    const float4* __restrict__ x4   = reinterpret_cast<const float4*>(x);
    const float4* __restrict__ phi4 = reinterpret_cast<const float4*>(phiws);

    const int bid  = blockIdx.x;
    const int kb   = bid & 1;
    const int b0   = (bid >> 1) * 8;
    const int wave = threadIdx.x >> 6;
    const int lane = threadIdx.x & 63;
    const int wv   = __builtin_amdgcn_readfirstlane(wave);

    __shared__ float4 xs[2][8][256];

    const int kbase = kb * 2048;
    const float4* __restrict__ srcw    = x4 + (size_t)(b0 + wave) * NC4 + kbase + lane;
    const float4* __restrict__ phibase = phi4 + (size_t)(wave * 3) * NC4 + kbase + lane;

    float acc[8][3];
#pragma unroll
    for (int r = 0; r < 8; ++r)
#pragma unroll
        for (int j = 0; j < 3; ++j) acc[r][j] = 0.f;
    float ssq = 0.f;

#pragma unroll 1
    for (int rep = 0; rep < 3; ++rep) {
        if constexpr (USE_DMA) {
#pragma unroll
            for (int i = 0; i < 4; ++i)
                ASYNC_COPY16(srcw + i * 64, &xs[0][wave][i * 64]);
        }
        if constexpr (USE_BAR) __syncthreads();

        int cur = 0;
#pragma unroll 1
        for (int c = 0; c < 8; ++c) {
            if constexpr (USE_DMA) {
                if (c < 7) {
#pragma unroll
                    for (int i = 0; i < 4; ++i)
                        ASYNC_COPY16(srcw + (c + 1) * 256 + i * 64,
                                     &xs[cur ^ 1][wave][i * 64]);
                }
            }

            const float4* __restrict__ pb = phibase + c * 256;
#pragma unroll 1
            for (int u = 0; u < 4; ++u) {
                const int ki = u * 64 + lane;

                float4 p0, p1, p2;
                if constexpr (USE_PHI) {
                    p0 = pb[(size_t)0 * NC4 + u * 64];
                    p1 = pb[(size_t)1 * NC4 + u * 64];
                    p2 = pb[(size_t)2 * NC4 + u * 64];
                } else {
                    p0 = make_float4(0.50f, 0.25f, 0.125f, 0.0625f);
                    p1 = make_float4(0.30f, 0.20f, 0.100f, 0.0500f);
                    p2 = make_float4(0.70f, 0.60f, 0.400f, 0.9000f);
                }

                float4 xw;
                if constexpr (USE_LDSR) xw = xs[cur][wv][ki];
                else                    xw = make_float4(0.11f, 0.22f, 0.33f, 0.44f);
                ssq += xw.x*xw.x + xw.y*xw.y + xw.z*xw.z + xw.w*xw.w;

#pragma unroll
                for (int r = 0; r < 8; ++r) {
                    float4 xv;
                    if constexpr (USE_LDSR) xv = xs[cur][r][ki];
                    else xv = make_float4(0.1f + r * 0.1f, 0.2f + r * 0.05f,
                                          0.3f, 0.4f);
                    acc[r][0] += xv.x*p0.x + xv.y*p0.y + xv.z*p0.z + xv.w*p0.w;
                    acc[r][1] += xv.x*p1.x + xv.y*p1.y + xv.z*p1.z + xv.w*p1.w;
                    acc[r][2] += xv.x*p2.x + xv.y*p2.y + xv.z*p2.z + xv.w*p2.w;
                }
            }

            if constexpr (USE_BAR) __syncthreads();
            cur ^= 1;
        }
    }

    // reduce everything into one live value -> sink (scratch, reused ws)
    float tot = ssq;
#pragma unroll
    for (int r = 0; r < 8; ++r)
#pragma unroll
        for (int j = 0; j < 3; ++j) tot += acc[r][j];
#pragma unroll
    for (int off = 32; off > 0; off >>= 1)
        tot += __shfl_xor(tot, off, 64);
    if (lane == 0) sink[(size_t)bid * 8 + wave] = tot;
}

// ---------------------------------------------------------------------------
// Kernel 2: per-row finalize (unchanged).
// ---------------------------------------------------------------------------
__global__ void finalize_kernel(
    const float* __restrict__ dots_part,
    const float* __restrict__ b_pre,
    const float* __restrict__ b_post,
    const float* __restrict__ b_res,
    const float* __restrict__ alpha_pre,
    const float* __restrict__ alpha_post,
    const float* __restrict__ alpha_res,
    float* __restrict__ params)
{
    const int row = blockIdx.x * blockDim.x + threadIdx.x;
    if (row >= B_ROWS) return;

    const float* d0 = dots_part + (size_t)row * 25;
    const float* d1 = dots_part + ((size_t)B_ROWS + row) * 25;
    float d[25];
#pragma unroll
    for (int o = 0; o < 25; ++o) d[o] = d0[o] + d1[o];

    const float inv_rms = rsqrtf(d[24] * (1.f / (float)NC) + 1e-8f);
    const float ap  = alpha_pre[0];
    const float apo = alpha_post[0];
    const float ar  = alpha_res[0];

    float hp[4];
    float mx = -1e30f;
#pragma unroll
    for (int j = 0; j < 4; ++j) {
        hp[j] = ap * d[j] * inv_rms + b_pre[j];
        mx = fmaxf(mx, hp[j]);
    }
    float e[4], s = 0.f;
#pragma unroll
    for (int j = 0; j < 4; ++j) { e[j] = expf(hp[j] - mx); s += e[j]; }
    float Hpre[4];
#pragma unroll
    for (int j = 0; j < 4; ++j) Hpre[j] = e[j] / s;

    float Hpost[4];
#pragma unroll
    for (int j = 0; j < 4; ++j) {
        const float h = apo * d[4 + j] * inv_rms + b_post[j];
        Hpost[j] = 2.f / (1.f + expf(-h));
    }

    float M[16];
#pragma unroll
    for (int k = 0; k < 16; ++k)
        M[k] = expf(ar * d[8 + k] * inv_rms + b_res[k]);

    for (int it = 0; it < 20; ++it) {
#pragma unroll
        for (int i = 0; i < 4; ++i) {
            const float rs = M[i*4+0] + M[i*4+1] + M[i*4+2] + M[i*4+3] + 1e-8f;
#pragma unroll
            for (int j = 0; j < 4; ++j) M[i*4+j] = M[i*4+j] / rs;
        }
#pragma unroll
        for (int j = 0; j < 4; ++j) {
            const float cs = M[0*4+j] + M[1*4+j] + M[2*4+j] + M[3*4+j] + 1e-8f;
#pragma unroll
            for (int i = 0; i < 4; ++i) M[i*4+j] = M[i*4+j] / cs;
        }
    }

    float* p = params + (size_t)row * 24;
#pragma unroll
    for (int j = 0; j < 4; ++j)  p[j]     = Hpre[j];
#pragma unroll
    for (int j = 0; j < 4; ++j)  p[4 + j] = Hpost[j];
#pragma unroll
    for (int k = 0; k < 16; ++k) p[8 + k] = M[k];
}

// ---------------------------------------------------------------------------
// Kernel 3: output (unchanged).
// ---------------------------------------------------------------------------
__global__ __launch_bounds__(256, 2) void out_kernel(
    const float* __restrict__ x,
    const float* __restrict__ w,
    const float* __restrict__ params,
    float* __restrict__ out)
{
    const float4* __restrict__ x4 = reinterpret_cast<const float4*>(x);
    const float4* __restrict__ w4 = reinterpret_cast<const float4*>(w);
    float4* __restrict__ out4 = reinterpret_cast<float4*>(out);

    const int b = blockIdx.x;
    const float* __restrict__ p = params + (size_t)b * 24;

    float Hpre[4], Hpost[4], M[16];
#pragma unroll
    for (int j = 0; j < 4; ++j)  Hpre[j]  = p[j];
#pragma unroll
    for (int j = 0; j < 4; ++j)  Hpost[j] = p[4 + j];
#pragma unroll
    for (int k = 0; k < 16; ++k) M[k]     = p[8 + k];

    const int t = threadIdx.x;
    const size_t base = (size_t)b * NC4;

    float4 xv[4][4];
    float4 agg[4];
    float ssq = 0.f;

#pragma unroll
    for (int u = 0; u < 4; ++u) {
        const int c4 = u * 256 + t;
#pragma unroll
        for (int n = 0; n < 4; ++n)
            xv[u][n] = x4[base + (size_t)n * C4 + c4];

        float4 a;
        a.x = Hpre[0]*xv[u][0].x + Hpre[1]*xv[u][1].x + Hpre[2]*xv[u][2].x + Hpre[3]*xv[u][3].x;
        a.y = Hpre[0]*xv[u][0].y + Hpre[1]*xv[u][1].y + Hpre[2]*xv[u][2].y + Hpre[3]*xv[u][3].y;
        a.z = Hpre[0]*xv[u][0].z + Hpre[1]*xv[u][1].z + Hpre[2]*xv[u][2].z + Hpre[3]*xv[u][3].z;
        a.w = Hpre[0]*xv[u][0].w + Hpre[1]*xv[u][1].w + Hpre[2]*xv[u][2].w + Hpre[3]*xv[u][3].w;
        agg[u] = a;
        ssq += a.x*a.x + a.y*a.y + a.z*a.z + a.w*a.w;
    }

#pragma unroll
    for (int off = 32; off > 0; off >>= 1)
        ssq += __shfl_xor(ssq, off, 64);
    __shared__ float red[4];
    if ((t & 63) == 0) red[t >> 6] = ssq;
    __syncthreads();
    const float total = red[0] + red[1] + red[2] + red[3];
    const float inv = rsqrtf(total * (1.f / (float)C_DIM) + 1e-5f);

#pragma unroll
    for (int u = 0; u < 4; ++u) {
        const int c4 = u * 256 + t;
        const float4 wv = w4[c4];
        float4 y;
        y.x = agg[u].x * inv * wv.x;
        y.y = agg[u].y * inv * wv.y;
        y.z = agg[u].z * inv * wv.z;
        y.w = agg[u].w * inv * wv.w;

#pragma unroll
        for (int i = 0; i < 4; ++i) {
            float4 o;
            o.x = Hpost[i]*y.x + M[i*4+0]*xv[u][0].x + M[i*4+1]*xv[u][1].x
                               + M[i*4+2]*xv[u][2].x + M[i*4+3]*xv[u][3].x;
            o.y = Hpost[i]*y.y + M[i*4+0]*xv[u][0].y + M[i*4+1]*xv[u][1].y
                               + M[i*4+2]*xv[u][2].y + M[i*4+3]*xv[u][3].y;
            o.z = Hpost[i]*y.z + M[i*4+0]*xv[u][0].z + M[i*4+1]*xv[u][1].z
                               + M[i*4+2]*xv[u][2].z + M[i*4+3]*xv[u][3].z;
            o.w = Hpost[i]*y.w + M[i*4+0]*xv[u][0].w + M[i*4+1]*xv[u][1].w
                               + M[i*4+2]*xv[u][2].w + M[i*4+3]*xv[u][3].w;
            out4[base + (size_t)i * C4 + c4] = o;
        }
    }
}

// ---------------------------------------------------------------------------
extern "C" void kernel_launch(void* const* d_in, const int* in_sizes, int n_in,
                              void* d_out, int out_size, void* d_ws, size_t ws_size,
                              hipStream_t stream) {
    const float* x        = (const float*)d_in[0];
    const float* w        = (const float*)d_in[1];
    const float* phi_pre  = (const float*)d_in[2];
    const float* phi_post = (const float*)d_in[3];
    const float* phi_res  = (const float*)d_in[4];
    const float* b_pre    = (const float*)d_in[5];
    const float* b_post   = (const float*)d_in[6];
    const float* b_res    = (const float*)d_in[7];
    const float* a_pre    = (const float*)d_in[8];
    const float* a_post   = (const float*)d_in[9];
    const float* a_res    = (const float*)d_in[10];
    float* out = (float*)d_out;

    float* dots_part = (float*)d_ws;                        // [2][4096][25]
    float* params    = dots_part + (size_t)2 * B_ROWS * 25; // [4096][24]
    float* phiws     = params + (size_t)B_ROWS * 24;        // [24][16384]

    hipLaunchKernelGGL(repack_kernel, dim3((24 * NC4 + 255) / 256), dim3(256), 0, stream,
                       (const float4*)phi_pre, (const float4*)phi_post,
                       (const float4*)phi_res, (float4*)phiws);
    hipLaunchKernelGGL(proj_kernel, dim3(B_ROWS / 4), dim3(512), 0, stream,
                       x, phiws, dots_part);
    hipLaunchKernelGGL(finalize_kernel, dim3(B_ROWS / 256), dim3(256), 0, stream,
                       dots_part, b_pre, b_post, b_res, a_pre, a_post, a_res, params);
    hipLaunchKernelGGL(out_kernel, dim3(B_ROWS), dim3(256), 0, stream,
                       x, w, params, out);

    // ---- diagnostic ablations (after out; sink reuses consumed dots region)
    float* sink = dots_part;   // dots already consumed by finalize this launch
    hipLaunchKernelGGL(proj_abl<0>, dim3(B_ROWS / 4), dim3(512), 0, stream, x, phiws, sink);
    hipLaunchKernelGGL(proj_abl<1>, dim3(B_ROWS / 4), dim3(512), 0, stream, x, phiws, sink);
    hipLaunchKernelGGL(proj_abl<2>, dim3(B_ROWS / 4), dim3(512), 0, stream, x, phiws, sink);
    hipLaunchKernelGGL(proj_abl<3>, dim3(B_ROWS / 4), dim3(512), 0, stream, x, phiws, sink);
    hipLaunchKernelGGL(proj_abl<4>, dim3(B_ROWS / 4), dim3(512), 0, stream, x, phiws, sink);
}

// Round 11
// 217.693 us; speedup vs baseline: 6.1927x; 6.1927x over previous
//
#include <hip/hip_runtime.h>
#include <math.h>

#define B_ROWS 4096
#define NSTR 4
#define C_DIM 4096
#define NC 16384      // NSTR*C_DIM
#define NC4 4096      // NC/4 (float4 per batch row)
#define C4 1024       // C_DIM/4 (float4 per stream)

// async global->LDS DMA, 16B per lane. LDS dest must be wave-uniform base;
// lane l writes base + l*16. Global src is per-lane.
#define ASYNC_COPY16(g, l)                                                     \
    __builtin_amdgcn_global_load_lds(                                         \
        (const __attribute__((address_space(1))) void*)(g),                   \
        (__attribute__((address_space(3))) void*)(l), 16, 0, 0)

// ---------------------------------------------------------------------------
// Kernel 0: repack phi into one contiguous [24][16384] buffer.
// Row order: [pre0..3, post0..3, res0..15]
// ---------------------------------------------------------------------------
__global__ void repack_kernel(
    const float4* __restrict__ pre4,
    const float4* __restrict__ post4,
    const float4* __restrict__ res4,
    float4* __restrict__ phiws4)
{
    const int idx = blockIdx.x * blockDim.x + threadIdx.x;   // 0 .. 24*4096-1
    if (idx >= 24 * NC4) return;
    const int row = idx / NC4;
    const int k4  = idx % NC4;
    float4 v;
    if (row < 4)        v = pre4[row * NC4 + k4];
    else if (row < 8)   v = post4[(row - 4) * NC4 + k4];
    else                v = res4[(row - 8) * NC4 + k4];
    phiws4[idx] = v;
}

// ---------------------------------------------------------------------------
// Kernel 1: projections. Grid = (B_ROWS/8) x 2 K-halves -> 1024 blocks of
// 256 threads (4 waves). Block = 8 batch rows x one K-half (2048 float4).
//
// R10 DIAGNOSIS: previous design (8 waves x 3 phi rows) was LDS-READ-PIPE
// bound: 9 ds_read_b128 (~108 LDS cyc) per 125 VALU-instr (~250 SIMD cyc)
// per u-step; 4 SIMDs share one LDS pipe -> demand ratio 4*108/250 = 1.7,
// predicting VALUBusy 58% == measured 62%.
//
// THIS DESIGN rebalances FMA : LDS-read by 2x:
//   - 4 waves/block; wave w owns phi rows 6w..6w+5 and DMA-stages x rows
//     2w, 2w+1 (global_load_lds, zero reg pressure, double-buffered).
//   - Per u-step: 8 ds_read_b128 feed 192 FMAs -> LDS demand ratio ~0.9.
//   - Nested fmaf chains: exactly 4 VALU per float4-dot (no mul+add).
//   - ssq folded into the r-loop via wave-uniform scalar branch on the
//     wave's own 2 rows (no extra LDS read, no dynamic reg indexing).
//   - chunk = 128 float4/row -> xs 32KB -> 4 blocks/CU, grid fully resident.
// Live floats ~ 48 acc + 24 phi + xv4 + ssq2 + addr ~15 = ~95 < 128 cap.
// Floors: VALU ~23us, x HBM 256MB ~41us, phi L2 805MB ~23us -> HBM-bound.
// ---------------------------------------------------------------------------
__global__ __launch_bounds__(256, 4) void proj_kernel(
    const float* __restrict__ x,
    const float* __restrict__ phiws,
    float* __restrict__ dots_part)   // [2][B_ROWS][25]
{
    const float4* __restrict__ x4   = reinterpret_cast<const float4*>(x);
    const float4* __restrict__ phi4 = reinterpret_cast<const float4*>(phiws);

    const int bid  = blockIdx.x;
    const int kb   = bid & 1;            // K-half
    const int b0   = (bid >> 1) * 8;     // first batch row
    const int wave = threadIdx.x >> 6;   // 0..3
    const int lane = threadIdx.x & 63;
    const int wv   = __builtin_amdgcn_readfirstlane(wave);  // SGPR wave id
    const int wr0  = 2 * wv;             // this wave's own rows (ssq)
    const int wr1  = 2 * wv + 1;

    __shared__ float4 xs[2][8][128];     // [buf][row][float4] = 32 KB
    __shared__ float  red[4][8][6];      // [wave][row][j]
    __shared__ float  redss[8];          // ssq per row

    const int kbase = kb * 2048;         // float4 index where this K-half starts

    // wave w stages rows 2w, 2w+1; per chunk each lane DMAs 2 float4s per row
    const float4* __restrict__ srcA = x4 + (size_t)(b0 + 2 * wave)     * NC4 + kbase + lane;
    const float4* __restrict__ srcB = x4 + (size_t)(b0 + 2 * wave + 1) * NC4 + kbase + lane;
    // wave w's 6 phi rows
    const float4* __restrict__ phibase = phi4 + (size_t)(wave * 6) * NC4 + kbase + lane;

    float acc[8][6];                     // [batch row][phi row j]
#pragma unroll
    for (int r = 0; r < 8; ++r)
#pragma unroll
        for (int j = 0; j < 6; ++j) acc[r][j] = 0.f;
    float ssq0 = 0.f, ssq1 = 0.f;        // sum x^2 of rows 2w, 2w+1

    // ---- prologue: DMA chunk 0 into buffer 0 ----
    ASYNC_COPY16(srcA,      &xs[0][2 * wave][0]);
    ASYNC_COPY16(srcA + 64, &xs[0][2 * wave][64]);
    ASYNC_COPY16(srcB,      &xs[0][2 * wave + 1][0]);
    ASYNC_COPY16(srcB + 64, &xs[0][2 * wave + 1][64]);
    __syncthreads();                     // drains vmcnt -> chunk 0 visible

    int cur = 0;
#pragma unroll 1
    for (int c = 0; c < 16; ++c) {
        // ---- DMA next chunk into the other buffer (in flight during consume)
        if (c < 15) {
            const int nf = (c + 1) * 128;
            ASYNC_COPY16(srcA + nf,      &xs[cur ^ 1][2 * wave][0]);
            ASYNC_COPY16(srcA + nf + 64, &xs[cur ^ 1][2 * wave][64]);
            ASYNC_COPY16(srcB + nf,      &xs[cur ^ 1][2 * wave + 1][0]);
            ASYNC_COPY16(srcB + nf + 64, &xs[cur ^ 1][2 * wave + 1][64]);
        }

        // ---- consume chunk c from xs[cur]: 2 u-steps of 64 float4s ----
        const float4* __restrict__ pb = phibase + c * 128;
#pragma unroll 1
        for (int u = 0; u < 2; ++u) {
            const int ki = u * 64 + lane;

            float4 p[6];
#pragma unroll
            for (int j = 0; j < 6; ++j)
                p[j] = pb[(size_t)j * NC4 + u * 64];

#pragma unroll
            for (int r = 0; r < 8; ++r) {
                const float4 xv = xs[cur][r][ki];
#pragma unroll
                for (int j = 0; j < 6; ++j) {
                    float a = acc[r][j];
                    a = fmaf(xv.x, p[j].x, a);
                    a = fmaf(xv.y, p[j].y, a);
                    a = fmaf(xv.z, p[j].z, a);
                    a = fmaf(xv.w, p[j].w, a);
                    acc[r][j] = a;
                }
                // ssq of this wave's own rows (wave-uniform scalar branch)
                if (r == wr0) {
                    ssq0 = fmaf(xv.x, xv.x, ssq0);
                    ssq0 = fmaf(xv.y, xv.y, ssq0);
                    ssq0 = fmaf(xv.z, xv.z, ssq0);
                    ssq0 = fmaf(xv.w, xv.w, ssq0);
                } else if (r == wr1) {
                    ssq1 = fmaf(xv.x, xv.x, ssq1);
                    ssq1 = fmaf(xv.y, xv.y, ssq1);
                    ssq1 = fmaf(xv.z, xv.z, ssq1);
                    ssq1 = fmaf(xv.w, xv.w, ssq1);
                }
            }
        }

        __syncthreads();     // next DMA chunk visible; all waves done with cur
        cur ^= 1;
    }

    // butterfly reduce across all 64 lanes (lanes cover distinct K positions)
#pragma unroll
    for (int r = 0; r < 8; ++r)
#pragma unroll
        for (int j = 0; j < 6; ++j) {
            float v = acc[r][j];
#pragma unroll
            for (int off = 32; off > 0; off >>= 1)
                v += __shfl_xor(v, off, 64);
            acc[r][j] = v;
        }
#pragma unroll
    for (int off = 32; off > 0; off >>= 1)
        ssq0 += __shfl_xor(ssq0, off, 64);
#pragma unroll
    for (int off = 32; off > 0; off >>= 1)
        ssq1 += __shfl_xor(ssq1, off, 64);

    if (lane == 0) {
#pragma unroll
        for (int r = 0; r < 8; ++r)
#pragma unroll
            for (int j = 0; j < 6; ++j)
                red[wave][r][j] = acc[r][j];
        redss[2 * wave]     = ssq0;
        redss[2 * wave + 1] = ssq1;
    }
    __syncthreads();

    // final gather; 200 threads -> dots_part[kb][8 rows][25]
    const int t = threadIdx.x;
    if (t < 200) {
        const int r = t / 25, o = t % 25;
        float s;
        if (o < 24) s = red[o / 6][r][o % 6];   // phi row o handled by wave o/6
        else        s = redss[r];               // ssq of row r
        dots_part[((size_t)kb * B_ROWS + (b0 + r)) * 25 + o] = s;
    }
}

// ---------------------------------------------------------------------------
// Kernel 2: per-row finalize: sum K-halves, rms factor, softmax, 2*sigmoid,
// Sinkhorn(20).
// dots layout: [0..3]=pre, [4..7]=post, [8..23]=res, [24]=ssq
// params layout: [0..3]=H_pre, [4..7]=H_post, [8..23]=M (row-major 4x4)
// ---------------------------------------------------------------------------
__global__ void finalize_kernel(
    const float* __restrict__ dots_part,
    const float* __restrict__ b_pre,
    const float* __restrict__ b_post,
    const float* __restrict__ b_res,
    const float* __restrict__ alpha_pre,
    const float* __restrict__ alpha_post,
    const float* __restrict__ alpha_res,
    float* __restrict__ params)
{
    const int row = blockIdx.x * blockDim.x + threadIdx.x;
    if (row >= B_ROWS) return;

    const float* d0 = dots_part + (size_t)row * 25;
    const float* d1 = dots_part + ((size_t)B_ROWS + row) * 25;
    float d[25];
#pragma unroll
    for (int o = 0; o < 25; ++o) d[o] = d0[o] + d1[o];

    const float inv_rms = rsqrtf(d[24] * (1.f / (float)NC) + 1e-8f);
    const float ap  = alpha_pre[0];
    const float apo = alpha_post[0];
    const float ar  = alpha_res[0];

    // softmax(h_pre)
    float hp[4];
    float mx = -1e30f;
#pragma unroll
    for (int j = 0; j < 4; ++j) {
        hp[j] = ap * d[j] * inv_rms + b_pre[j];
        mx = fmaxf(mx, hp[j]);
    }
    float e[4], s = 0.f;
#pragma unroll
    for (int j = 0; j < 4; ++j) { e[j] = expf(hp[j] - mx); s += e[j]; }
    float Hpre[4];
#pragma unroll
    for (int j = 0; j < 4; ++j) Hpre[j] = e[j] / s;

    // 2*sigmoid(h_post)
    float Hpost[4];
#pragma unroll
    for (int j = 0; j < 4; ++j) {
        const float h = apo * d[4 + j] * inv_rms + b_post[j];
        Hpost[j] = 2.f / (1.f + expf(-h));
    }

    // Sinkhorn on exp(h_res)
    float M[16];
#pragma unroll
    for (int k = 0; k < 16; ++k)
        M[k] = expf(ar * d[8 + k] * inv_rms + b_res[k]);

    for (int it = 0; it < 20; ++it) {
#pragma unroll
        for (int i = 0; i < 4; ++i) {
            const float rs = M[i*4+0] + M[i*4+1] + M[i*4+2] + M[i*4+3] + 1e-8f;
#pragma unroll
            for (int j = 0; j < 4; ++j) M[i*4+j] = M[i*4+j] / rs;
        }
#pragma unroll
        for (int j = 0; j < 4; ++j) {
            const float cs = M[0*4+j] + M[1*4+j] + M[2*4+j] + M[3*4+j] + 1e-8f;
#pragma unroll
            for (int i = 0; i < 4; ++i) M[i*4+j] = M[i*4+j] / cs;
        }
    }

    float* p = params + (size_t)row * 24;
#pragma unroll
    for (int j = 0; j < 4; ++j)  p[j]     = Hpre[j];
#pragma unroll
    for (int j = 0; j < 4; ++j)  p[4 + j] = Hpost[j];
#pragma unroll
    for (int k = 0; k < 16; ++k) p[8 + k] = M[k];
}

// ---------------------------------------------------------------------------
// Kernel 3: output. One block per batch row; x row held in registers
// (64 floats/thread), block-reduced RMS of x_agg, then fused epilogue.
// ---------------------------------------------------------------------------
__global__ __launch_bounds__(256, 2) void out_kernel(
    const float* __restrict__ x,
    const float* __restrict__ w,
    const float* __restrict__ params,
    float* __restrict__ out)
{
    const float4* __restrict__ x4 = reinterpret_cast<const float4*>(x);
    const float4* __restrict__ w4 = reinterpret_cast<const float4*>(w);
    float4* __restrict__ out4 = reinterpret_cast<float4*>(out);

    const int b = blockIdx.x;
    const float* __restrict__ p = params + (size_t)b * 24;

    float Hpre[4], Hpost[4], M[16];
#pragma unroll
    for (int j = 0; j < 4; ++j)  Hpre[j]  = p[j];
#pragma unroll
    for (int j = 0; j < 4; ++j)  Hpost[j] = p[4 + j];
#pragma unroll
    for (int k = 0; k < 16; ++k) M[k]     = p[8 + k];

    const int t = threadIdx.x;
    const size_t base = (size_t)b * NC4;

    float4 xv[4][4];
    float4 agg[4];
    float ssq = 0.f;

#pragma unroll
    for (int u = 0; u < 4; ++u) {
        const int c4 = u * 256 + t;
#pragma unroll
        for (int n = 0; n < 4; ++n)
            xv[u][n] = x4[base + (size_t)n * C4 + c4];

        float4 a;
        a.x = Hpre[0]*xv[u][0].x + Hpre[1]*xv[u][1].x + Hpre[2]*xv[u][2].x + Hpre[3]*xv[u][3].x;
        a.y = Hpre[0]*xv[u][0].y + Hpre[1]*xv[u][1].y + Hpre[2]*xv[u][2].y + Hpre[3]*xv[u][3].y;
        a.z = Hpre[0]*xv[u][0].z + Hpre[1]*xv[u][1].z + Hpre[2]*xv[u][2].z + Hpre[3]*xv[u][3].z;
        a.w = Hpre[0]*xv[u][0].w + Hpre[1]*xv[u][1].w + Hpre[2]*xv[u][2].w + Hpre[3]*xv[u][3].w;
        agg[u] = a;
        ssq += a.x*a.x + a.y*a.y + a.z*a.z + a.w*a.w;
    }

#pragma unroll
    for (int off = 32; off > 0; off >>= 1)
        ssq += __shfl_xor(ssq, off, 64);
    __shared__ float red[4];
    if ((t & 63) == 0) red[t >> 6] = ssq;
    __syncthreads();
    const float total = red[0] + red[1] + red[2] + red[3];
    const float inv = rsqrtf(total * (1.f / (float)C_DIM) + 1e-5f);

#pragma unroll
    for (int u = 0; u < 4; ++u) {
        const int c4 = u * 256 + t;
        const float4 wv = w4[c4];
        float4 y;
        y.x = agg[u].x * inv * wv.x;
        y.y = agg[u].y * inv * wv.y;
        y.z = agg[u].z * inv * wv.z;
        y.w = agg[u].w * inv * wv.w;

#pragma unroll
        for (int i = 0; i < 4; ++i) {
            float4 o;
            o.x = Hpost[i]*y.x + M[i*4+0]*xv[u][0].x + M[i*4+1]*xv[u][1].x
                               + M[i*4+2]*xv[u][2].x + M[i*4+3]*xv[u][3].x;
            o.y = Hpost[i]*y.y + M[i*4+0]*xv[u][0].y + M[i*4+1]*xv[u][1].y
                               + M[i*4+2]*xv[u][2].y + M[i*4+3]*xv[u][3].y;
            o.z = Hpost[i]*y.z + M[i*4+0]*xv[u][0].z + M[i*4+1]*xv[u][1].z
                               + M[i*4+2]*xv[u][2].z + M[i*4+3]*xv[u][3].z;
            o.w = Hpost[i]*y.w + M[i*4+0]*xv[u][0].w + M[i*4+1]*xv[u][1].w
                               + M[i*4+2]*xv[u][2].w + M[i*4+3]*xv[u][3].w;
            out4[base + (size_t)i * C4 + c4] = o;
        }
    }
}

// ---------------------------------------------------------------------------
extern "C" void kernel_launch(void* const* d_in, const int* in_sizes, int n_in,
                              void* d_out, int out_size, void* d_ws, size_t ws_size,
                              hipStream_t stream) {
    const float* x        = (const float*)d_in[0];
    const float* w        = (const float*)d_in[1];
    const float* phi_pre  = (const float*)d_in[2];
    const float* phi_post = (const float*)d_in[3];
    const float* phi_res  = (const float*)d_in[4];
    const float* b_pre    = (const float*)d_in[5];
    const float* b_post   = (const float*)d_in[6];
    const float* b_res    = (const float*)d_in[7];
    const float* a_pre    = (const float*)d_in[8];
    const float* a_post   = (const float*)d_in[9];
    const float* a_res    = (const float*)d_in[10];
    float* out = (float*)d_out;

    float* dots_part = (float*)d_ws;                        // [2][4096][25]
    float* params    = dots_part + (size_t)2 * B_ROWS * 25; // [4096][24]
    float* phiws     = params + (size_t)B_ROWS * 24;        // [24][16384]

    hipLaunchKernelGGL(repack_kernel, dim3((24 * NC4 + 255) / 256), dim3(256), 0, stream,
                       (const float4*)phi_pre, (const float4*)phi_post,
                       (const float4*)phi_res, (float4*)phiws);
    hipLaunchKernelGGL(proj_kernel, dim3(B_ROWS / 4), dim3(256), 0, stream,
                       x, phiws, dots_part);
    hipLaunchKernelGGL(finalize_kernel, dim3(B_ROWS / 256), dim3(256), 0, stream,
                       dots_part, b_pre, b_post, b_res, a_pre, a_post, a_res, params);
    hipLaunchKernelGGL(out_kernel, dim3(B_ROWS), dim3(256), 0, stream,
                       x, w, params, out);
}

// Round 12
// 203.002 us; speedup vs baseline: 6.6408x; 1.0724x over previous
//
#include <hip/hip_runtime.h>
#include <math.h>

#define B_ROWS 4096
#define NSTR 4
#define C_DIM 4096
#define NC 16384      // NSTR*C_DIM
#define NC4 4096      // NC/4 (float4 per batch row)
#define C4 1024       // C_DIM/4 (float4 per stream)

// async global->LDS DMA, 16B per lane. LDS dest must be wave-uniform base;
// lane l writes base + l*16. Global src is per-lane.
#define ASYNC_COPY16(g, l)                                                     \
    __builtin_amdgcn_global_load_lds(                                         \
        (const __attribute__((address_space(1))) void*)(g),                   \
        (__attribute__((address_space(3))) void*)(l), 16, 0, 0)

#define DOT4(A, P, XV) { float _a = (A);                                       \
    _a = fmaf((XV).x, (P).x, _a); _a = fmaf((XV).y, (P).y, _a);                \
    _a = fmaf((XV).z, (P).z, _a); _a = fmaf((XV).w, (P).w, _a); (A) = _a; }

// ---------------------------------------------------------------------------
// Kernel 1: projections. Grid = (B_ROWS/8) x 2 K-halves -> 1024 blocks of
// 256 threads (4 waves). Block = 8 batch rows x one K-half (2048 float4).
// Wave w owns phi rows 6w..6w+5 (direct pre/post/res pointer select, no
// repack) and DMA-stages x rows 2w,2w+1.
//
// R11 POST-MORTEM (the key ISA fact): vmcnt retires IN ORDER. With DMAs
// issued before the phi loads, the compiler's wait for the first phi use
// could not retire until ALL in-flight HBM DMAs retired -> every u-step
// chained on the staging loads; __syncthreads additionally drained
// vmcnt(0) every chunk. Double-buffering was structurally defeated.
//
// THIS SCHEDULE (T3/T4 counted-vmcnt, 3 buffers, chunk=64 float4/row):
//   per iter c: [s_waitcnt vmcnt(8)  -- counted: exactly phi(c-1)x6 +
//                dma(c+1)x2 were issued after chunk c's DMA]
//               [raw s_barrier -- NO vmcnt(0) drain]
//               [6 phi loads for chunk c FIRST]
//               [then DMA chunk c+2 -> buf (c+2)%3]   <- phi waits now leave
//               [8 ds_read + 192 FMA consume]            the DMA in flight
// sched_barrier(0) pins the issue order the counts rely on.
// Prefetch distance: explicit wait is 2 iterations; in-order phi chaining
// distance is 1 full consume phase (~4x460 wall cycles at 4 waves/SIMD)
// >= HBM latency.
// LDS: 3x8KB xs + red = ~25KB -> 4 blocks/CU (grid fully resident).
// ---------------------------------------------------------------------------
__global__ __launch_bounds__(256, 4) void proj_kernel(
    const float* __restrict__ x,
    const float* __restrict__ phi_pre,
    const float* __restrict__ phi_post,
    const float* __restrict__ phi_res,
    float* __restrict__ dots_part)   // [2][B_ROWS][25]
{
    const float4* __restrict__ x4    = reinterpret_cast<const float4*>(x);
    const float4* __restrict__ pre4  = reinterpret_cast<const float4*>(phi_pre);
    const float4* __restrict__ post4 = reinterpret_cast<const float4*>(phi_post);
    const float4* __restrict__ res4  = reinterpret_cast<const float4*>(phi_res);

    const int bid  = blockIdx.x;
    const int kb   = bid & 1;            // K-half
    const int b0   = (bid >> 1) * 8;     // first batch row
    const int wave = threadIdx.x >> 6;   // 0..3
    const int lane = threadIdx.x & 63;
    const int wv   = __builtin_amdgcn_readfirstlane(wave);
    const int wr0  = 2 * wv;             // this wave's own rows (ssq)
    const int wr1  = 2 * wv + 1;

    __shared__ float4 xs[3][8][64];      // [buf][row][float4] = 24 KB
    __shared__ float  red[4][8][6];      // [wave][row][j]
    __shared__ float  redss[8];          // ssq per row

    const int kbase = kb * 2048;         // float4 index where this K-half starts

    // x staging pointers (advance by 64/iter; point at current chunk c)
    const float4* srcA = x4 + (size_t)(b0 + 2 * wave)     * NC4 + kbase + lane;
    const float4* srcB = x4 + (size_t)(b0 + 2 * wave + 1) * NC4 + kbase + lane;

    // wave's 6 phi row pointers, direct from the three inputs (no repack).
    // row indices wave*6+j, j=0..5; selection is wave-uniform.
    const int row0 = wv * 6;
    auto rowbase = [&](int row) -> const float4* {
        if (row < 4)  return pre4  + (size_t)row * NC4;
        if (row < 8)  return post4 + (size_t)(row - 4) * NC4;
        return res4 + (size_t)(row - 8) * NC4;
    };
    const float4* pb0 = rowbase(row0 + 0) + kbase + lane;
    const float4* pb1 = rowbase(row0 + 1) + kbase + lane;
    const float4* pb2 = rowbase(row0 + 2) + kbase + lane;
    const float4* pb3 = rowbase(row0 + 3) + kbase + lane;
    const float4* pb4 = rowbase(row0 + 4) + kbase + lane;
    const float4* pb5 = rowbase(row0 + 5) + kbase + lane;

    float acc[8][6];
#pragma unroll
    for (int r = 0; r < 8; ++r)
#pragma unroll
        for (int j = 0; j < 6; ++j) acc[r][j] = 0.f;
    float ssq0 = 0.f, ssq1 = 0.f;

    // ---- prologue: DMA chunk 0 -> buf0, chunk 1 -> buf1 (4 vmem ops) ----
    ASYNC_COPY16(srcA,      &xs[0][2 * wave][0]);
    ASYNC_COPY16(srcB,      &xs[0][2 * wave + 1][0]);
    ASYNC_COPY16(srcA + 64, &xs[1][2 * wave][0]);
    ASYNC_COPY16(srcB + 64, &xs[1][2 * wave + 1][0]);
    __builtin_amdgcn_sched_barrier(0);

    int bc = 0;   // buffer holding chunk c
    int bf = 2;   // buffer to fill with chunk c+2

#pragma unroll 1
    for (int c = 0; c < 32; ++c) {
        // -- 1. counted wait: chunk c's 2 DMAs retired (in-order counter).
        //    ops issued after them: phi(c-1) x6 + dma(c+1) x2 = 8 (steady);
        //    c==0: only dma(c1) x2; c==31: drain (cheap, only phi left).
        if (c == 0)       asm volatile("s_waitcnt vmcnt(2)" ::: "memory");
        else if (c == 31) asm volatile("s_waitcnt vmcnt(0)" ::: "memory");
        else              asm volatile("s_waitcnt vmcnt(8)" ::: "memory");
        __builtin_amdgcn_sched_barrier(0);
        __builtin_amdgcn_s_barrier();        // raw: no vmcnt(0) drain
        __builtin_amdgcn_sched_barrier(0);

        // -- 2. phi loads for chunk c FIRST (before any new DMA) --
        const float4 p0 = *pb0;
        const float4 p1 = *pb1;
        const float4 p2 = *pb2;
        const float4 p3 = *pb3;
        const float4 p4 = *pb4;
        const float4 p5 = *pb5;
        __builtin_amdgcn_sched_barrier(0);

        // -- 3. prefetch chunk c+2 into bf (holds chunk c-1: consumed by all,
        //    guaranteed by the barrier above) --
        if (c < 30) {
            ASYNC_COPY16(srcA + 128, &xs[bf][2 * wave][0]);
            ASYNC_COPY16(srcB + 128, &xs[bf][2 * wave + 1][0]);
        }
        __builtin_amdgcn_sched_barrier(0);

        // -- 4. consume chunk c: 8 ds_read_b128 + 192 FMAs --
#pragma unroll
        for (int r = 0; r < 8; ++r) {
            const float4 xv = xs[bc][r][lane];
            DOT4(acc[r][0], p0, xv);
            DOT4(acc[r][1], p1, xv);
            DOT4(acc[r][2], p2, xv);
            DOT4(acc[r][3], p3, xv);
            DOT4(acc[r][4], p4, xv);
            DOT4(acc[r][5], p5, xv);
            if (r == wr0)      DOT4(ssq0, xv, xv)
            else if (r == wr1) DOT4(ssq1, xv, xv)
        }

        // advance
        srcA += 64; srcB += 64;
        pb0 += 64; pb1 += 64; pb2 += 64; pb3 += 64; pb4 += 64; pb5 += 64;
        bc = (bc == 2) ? 0 : bc + 1;
        bf = (bf == 2) ? 0 : bf + 1;
    }

    // butterfly reduce across all 64 lanes (lanes cover distinct K positions)
#pragma unroll
    for (int r = 0; r < 8; ++r)
#pragma unroll
        for (int j = 0; j < 6; ++j) {
            float v = acc[r][j];
#pragma unroll
            for (int off = 32; off > 0; off >>= 1)
                v += __shfl_xor(v, off, 64);
            acc[r][j] = v;
        }
#pragma unroll
    for (int off = 32; off > 0; off >>= 1)
        ssq0 += __shfl_xor(ssq0, off, 64);
#pragma unroll
    for (int off = 32; off > 0; off >>= 1)
        ssq1 += __shfl_xor(ssq1, off, 64);

    if (lane == 0) {
#pragma unroll
        for (int r = 0; r < 8; ++r)
#pragma unroll
            for (int j = 0; j < 6; ++j)
                red[wave][r][j] = acc[r][j];
        redss[2 * wave]     = ssq0;
        redss[2 * wave + 1] = ssq1;
    }
    __syncthreads();

    // final gather; 200 threads -> dots_part[kb][8 rows][25]
    const int t = threadIdx.x;
    if (t < 200) {
        const int r = t / 25, o = t % 25;
        float s;
        if (o < 24) s = red[o / 6][r][o % 6];   // phi row o handled by wave o/6
        else        s = redss[r];               // ssq of row r
        dots_part[((size_t)kb * B_ROWS + (b0 + r)) * 25 + o] = s;
    }
}

// ---------------------------------------------------------------------------
// Kernel 2: per-row finalize: sum K-halves, rms factor, softmax, 2*sigmoid,
// Sinkhorn(20).
// dots layout: [0..3]=pre, [4..7]=post, [8..23]=res, [24]=ssq
// params layout: [0..3]=H_pre, [4..7]=H_post, [8..23]=M (row-major 4x4)
// ---------------------------------------------------------------------------
__global__ void finalize_kernel(
    const float* __restrict__ dots_part,
    const float* __restrict__ b_pre,
    const float* __restrict__ b_post,
    const float* __restrict__ b_res,
    const float* __restrict__ alpha_pre,
    const float* __restrict__ alpha_post,
    const float* __restrict__ alpha_res,
    float* __restrict__ params)
{
    const int row = blockIdx.x * blockDim.x + threadIdx.x;
    if (row >= B_ROWS) return;

    const float* d0 = dots_part + (size_t)row * 25;
    const float* d1 = dots_part + ((size_t)B_ROWS + row) * 25;
    float d[25];
#pragma unroll
    for (int o = 0; o < 25; ++o) d[o] = d0[o] + d1[o];

    const float inv_rms = rsqrtf(d[24] * (1.f / (float)NC) + 1e-8f);
    const float ap  = alpha_pre[0];
    const float apo = alpha_post[0];
    const float ar  = alpha_res[0];

    // softmax(h_pre)
    float hp[4];
    float mx = -1e30f;
#pragma unroll
    for (int j = 0; j < 4; ++j) {
        hp[j] = ap * d[j] * inv_rms + b_pre[j];
        mx = fmaxf(mx, hp[j]);
    }
    float e[4], s = 0.f;
#pragma unroll
    for (int j = 0; j < 4; ++j) { e[j] = expf(hp[j] - mx); s += e[j]; }
    float Hpre[4];
#pragma unroll
    for (int j = 0; j < 4; ++j) Hpre[j] = e[j] / s;

    // 2*sigmoid(h_post)
    float Hpost[4];
#pragma unroll
    for (int j = 0; j < 4; ++j) {
        const float h = apo * d[4 + j] * inv_rms + b_post[j];
        Hpost[j] = 2.f / (1.f + expf(-h));
    }

    // Sinkhorn on exp(h_res)
    float M[16];
#pragma unroll
    for (int k = 0; k < 16; ++k)
        M[k] = expf(ar * d[8 + k] * inv_rms + b_res[k]);

    for (int it = 0; it < 20; ++it) {
#pragma unroll
        for (int i = 0; i < 4; ++i) {
            const float rs = M[i*4+0] + M[i*4+1] + M[i*4+2] + M[i*4+3] + 1e-8f;
#pragma unroll
            for (int j = 0; j < 4; ++j) M[i*4+j] = M[i*4+j] / rs;
        }
#pragma unroll
        for (int j = 0; j < 4; ++j) {
            const float cs = M[0*4+j] + M[1*4+j] + M[2*4+j] + M[3*4+j] + 1e-8f;
#pragma unroll
            for (int i = 0; i < 4; ++i) M[i*4+j] = M[i*4+j] / cs;
        }
    }

    float* p = params + (size_t)row * 24;
#pragma unroll
    for (int j = 0; j < 4; ++j)  p[j]     = Hpre[j];
#pragma unroll
    for (int j = 0; j < 4; ++j)  p[4 + j] = Hpost[j];
#pragma unroll
    for (int k = 0; k < 16; ++k) p[8 + k] = M[k];
}

// ---------------------------------------------------------------------------
// Kernel 3: output. One block per batch row; x row held in registers
// (64 floats/thread), block-reduced RMS of x_agg, then fused epilogue.
// ---------------------------------------------------------------------------
__global__ __launch_bounds__(256, 2) void out_kernel(
    const float* __restrict__ x,
    const float* __restrict__ w,
    const float* __restrict__ params,
    float* __restrict__ out)
{
    const float4* __restrict__ x4 = reinterpret_cast<const float4*>(x);
    const float4* __restrict__ w4 = reinterpret_cast<const float4*>(w);
    float4* __restrict__ out4 = reinterpret_cast<float4*>(out);

    const int b = blockIdx.x;
    const float* __restrict__ p = params + (size_t)b * 24;

    float Hpre[4], Hpost[4], M[16];
#pragma unroll
    for (int j = 0; j < 4; ++j)  Hpre[j]  = p[j];
#pragma unroll
    for (int j = 0; j < 4; ++j)  Hpost[j] = p[4 + j];
#pragma unroll
    for (int k = 0; k < 16; ++k) M[k]     = p[8 + k];

    const int t = threadIdx.x;
    const size_t base = (size_t)b * NC4;

    float4 xv[4][4];
    float4 agg[4];
    float ssq = 0.f;

#pragma unroll
    for (int u = 0; u < 4; ++u) {
        const int c4 = u * 256 + t;
#pragma unroll
        for (int n = 0; n < 4; ++n)
            xv[u][n] = x4[base + (size_t)n * C4 + c4];

        float4 a;
        a.x = Hpre[0]*xv[u][0].x + Hpre[1]*xv[u][1].x + Hpre[2]*xv[u][2].x + Hpre[3]*xv[u][3].x;
        a.y = Hpre[0]*xv[u][0].y + Hpre[1]*xv[u][1].y + Hpre[2]*xv[u][2].y + Hpre[3]*xv[u][3].y;
        a.z = Hpre[0]*xv[u][0].z + Hpre[1]*xv[u][1].z + Hpre[2]*xv[u][2].z + Hpre[3]*xv[u][3].z;
        a.w = Hpre[0]*xv[u][0].w + Hpre[1]*xv[u][1].w + Hpre[2]*xv[u][2].w + Hpre[3]*xv[u][3].w;
        agg[u] = a;
        ssq += a.x*a.x + a.y*a.y + a.z*a.z + a.w*a.w;
    }

#pragma unroll
    for (int off = 32; off > 0; off >>= 1)
        ssq += __shfl_xor(ssq, off, 64);
    __shared__ float red[4];
    if ((t & 63) == 0) red[t >> 6] = ssq;
    __syncthreads();
    const float total = red[0] + red[1] + red[2] + red[3];
    const float inv = rsqrtf(total * (1.f / (float)C_DIM) + 1e-5f);

#pragma unroll
    for (int u = 0; u < 4; ++u) {
        const int c4 = u * 256 + t;
        const float4 wv = w4[c4];
        float4 y;
        y.x = agg[u].x * inv * wv.x;
        y.y = agg[u].y * inv * wv.y;
        y.z = agg[u].z * inv * wv.z;
        y.w = agg[u].w * inv * wv.w;

#pragma unroll
        for (int i = 0; i < 4; ++i) {
            float4 o;
            o.x = Hpost[i]*y.x + M[i*4+0]*xv[u][0].x + M[i*4+1]*xv[u][1].x
                               + M[i*4+2]*xv[u][2].x + M[i*4+3]*xv[u][3].x;
            o.y = Hpost[i]*y.y + M[i*4+0]*xv[u][0].y + M[i*4+1]*xv[u][1].y
                               + M[i*4+2]*xv[u][2].y + M[i*4+3]*xv[u][3].y;
            o.z = Hpost[i]*y.z + M[i*4+0]*xv[u][0].z + M[i*4+1]*xv[u][1].z
                               + M[i*4+2]*xv[u][2].z + M[i*4+3]*xv[u][3].z;
            o.w = Hpost[i]*y.w + M[i*4+0]*xv[u][0].w + M[i*4+1]*xv[u][1].w
                               + M[i*4+2]*xv[u][2].w + M[i*4+3]*xv[u][3].w;
            out4[base + (size_t)i * C4 + c4] = o;
        }
    }
}

// ---------------------------------------------------------------------------
extern "C" void kernel_launch(void* const* d_in, const int* in_sizes, int n_in,
                              void* d_out, int out_size, void* d_ws, size_t ws_size,
                              hipStream_t stream) {
    const float* x        = (const float*)d_in[0];
    const float* w        = (const float*)d_in[1];
    const float* phi_pre  = (const float*)d_in[2];
    const float* phi_post = (const float*)d_in[3];
    const float* phi_res  = (const float*)d_in[4];
    const float* b_pre    = (const float*)d_in[5];
    const float* b_post   = (const float*)d_in[6];
    const float* b_res    = (const float*)d_in[7];
    const float* a_pre    = (const float*)d_in[8];
    const float* a_post   = (const float*)d_in[9];
    const float* a_res    = (const float*)d_in[10];
    float* out = (float*)d_out;

    float* dots_part = (float*)d_ws;                        // [2][4096][25]
    float* params    = dots_part + (size_t)2 * B_ROWS * 25; // [4096][24]

    hipLaunchKernelGGL(proj_kernel, dim3(B_ROWS / 4), dim3(256), 0, stream,
                       x, phi_pre, phi_post, phi_res, dots_part);
    hipLaunchKernelGGL(finalize_kernel, dim3(B_ROWS / 256), dim3(256), 0, stream,
                       dots_part, b_pre, b_post, b_res, a_pre, a_post, a_res, params);
    hipLaunchKernelGGL(out_kernel, dim3(B_ROWS), dim3(256), 0, stream,
                       x, w, params, out);
}